// Round 12
// baseline (385.402 us; speedup 1.0000x reference)
//
#include <hip/hip_runtime.h>

// RGCN pruned to the 2-hop cone of the first 1024 nodes.
// R12: 8 graph nodes. scatter2 fused into conv1's epilogue (edges bucketed
// by src S1-tile in compact0; conv1 scatters from LDS-staged bf16 h1 tile,
// aliased over dead As/Bs). scatter1 grid-stride capped at 2048 blocks.
// prep zero at 32B/thread. R11 measured 379.4us @ absmax 1.95e-3.

#define N_NODES 100000
#define N_EDGES 400000
#define IN_DIM  768
#define HID     256
#define OUT_DIM 128
#define NREL    3
#define BATCH   1024
#define KCAT    1024   // HID*(NREL+1)
#define MSGW    768    // NREL*HID
#define CAP0    32768  // |S0| ~23K
#define CAP1    8192   // |S1| ~5K
#define ECAP1   32768  // edges into S1 ~20K
#define ECAP2   8192   // edges into S2 ~4.1K
#define NTILE1  (CAP1 / 64)   // 128 S1 tiles
#define BKT2CAP 512           // edges per tile bucket (expected ~51)

typedef __attribute__((ext_vector_type(8))) short bf16x8;
typedef __attribute__((ext_vector_type(4))) float f32x4;

static __device__ __forceinline__ int imin(int a, int b) { return a < b ? a : b; }

static __device__ __forceinline__ unsigned short f2bf(float f) {
    union { float f; unsigned int u; } v; v.f = f;
    unsigned int r = v.u + 0x7FFFu + ((v.u >> 16) & 1u);   // RNE
    return (unsigned short)(r >> 16);
}

static __device__ __forceinline__ float bf2f(unsigned short h) {
    union { unsigned int u; float f; } c; c.u = ((unsigned int)h) << 16;
    return c.f;
}

#define P1n  ((IN_DIM * HID) / 8)    // 24576 w1s threads
#define P2n  ((KCAT * HID) / 8)      // 32768 per B1s/B2s
#define PW2n ((HID * OUT_DIM) / 8)   // 4096 W2t threads

// ---------------- N1: Amsg zero (32B/thread) + weight prep + mark1c ----------------
__global__ __launch_bounds__(256) void prep_mark1(
    uint4* __restrict__ zp, int nzA2,
    const float* __restrict__ W1,
    const float* __restrict__ c1root, const float* __restrict__ c1W,
    const float* __restrict__ c2root, const float* __restrict__ c2W,
    const float* __restrict__ W2,
    unsigned short* __restrict__ w1s,
    unsigned short* __restrict__ B1s,
    unsigned short* __restrict__ B2s,
    unsigned short* __restrict__ W2t,
    const int* __restrict__ ei, int* __restrict__ need1,
    int* __restrict__ elist2, int* __restrict__ ectr2)
{
    int t = blockIdx.x * blockDim.x + threadIdx.x;
    if (t < nzA2) {
        uint4 z = make_uint4(0u, 0u, 0u, 0u);
        zp[2 * t] = z;
        zp[2 * t + 1] = z;
        return;
    }
    int u = t - nzA2;
    if (u < P1n) {
        int base = u * 8;
        int j0 = base & 31, c = (base >> 5) & 255, s = base >> 13;
        unsigned int pk[4];
        #pragma unroll
        for (int q = 0; q < 4; q++) {
            unsigned short lo = f2bf(W1[((s * 32 + j0 + 2 * q) << 8) + c]);
            unsigned short hi = f2bf(W1[((s * 32 + j0 + 2 * q + 1) << 8) + c]);
            pk[q] = (unsigned int)lo | ((unsigned int)hi << 16);
        }
        *(uint4*)&w1s[base] = make_uint4(pk[0], pk[1], pk[2], pk[3]);
        return;
    }
    u -= P1n;
    if (u < 2 * P2n) {
        int which2 = u >= P2n;
        const float* root = which2 ? c2root : c1root;
        const float* Wr   = which2 ? c2W : c1W;
        unsigned short* dst = which2 ? B2s : B1s;
        int base = (u - (which2 ? P2n : 0)) * 8;
        int j0 = base & 31, c = (base >> 5) & 255, s = base >> 13;
        int k0 = s * 32 + j0;
        unsigned int pk[4];
        #pragma unroll
        for (int q = 0; q < 4; q++) {
            int ka = k0 + 2 * q, kb = ka + 1;
            float va = (ka < HID) ? root[(ka << 8) + c] : Wr[((ka - HID) << 8) + c];
            float vb = (kb < HID) ? root[(kb << 8) + c] : Wr[((kb - HID) << 8) + c];
            pk[q] = (unsigned int)f2bf(va) | ((unsigned int)f2bf(vb) << 16);
        }
        *(uint4*)&dst[base] = make_uint4(pk[0], pk[1], pk[2], pk[3]);
        return;
    }
    u -= 2 * P2n;
    if (u < PW2n) {
        int s = u >> 9, f = (u >> 6) & 7, l = u & 63;
        int kb = s * 32 + ((l >> 4) << 3);
        int c  = (f << 4) + (l & 15);
        unsigned int pk[4];
        #pragma unroll
        for (int q = 0; q < 4; q++) {
            unsigned short lo = f2bf(W2[(size_t)(kb + 2 * q)     * OUT_DIM + c]);
            unsigned short hi = f2bf(W2[(size_t)(kb + 2 * q + 1) * OUT_DIM + c]);
            pk[q] = (unsigned int)lo | ((unsigned int)hi << 16);
        }
        *(uint4*)&W2t[(size_t)u * 8] = make_uint4(pk[0], pk[1], pk[2], pk[3]);
        return;
    }
    u -= PW2n;
    if (u < N_EDGES) {
        if (ei[N_EDGES + u] < BATCH) {
            need1[ei[u]] = 1;   // benign same-value race
            int p = atomicAdd(ectr2, 1);
            if (p < ECAP2) elist2[p] = u;
        }
    }
}

// ---------------- N2: mark0c + compact S1 ----------------
__global__ void mark0_compact1(const int* __restrict__ ei, const int* __restrict__ need1,
                               int* __restrict__ need0,
                               int* __restrict__ elist1, int* __restrict__ ectr1,
                               int* __restrict__ idx1, int* __restrict__ map1,
                               int* __restrict__ n1ctr) {
    int t = blockIdx.x * blockDim.x + threadIdx.x;
    if (t < N_EDGES) {
        int d = ei[N_EDGES + t];
        if (d < BATCH || need1[d]) {
            need0[ei[t]] = 1;
            int p = atomicAdd(ectr1, 1);
            if (p < ECAP1) elist1[p] = t;
        }
        return;
    }
    int i = t - N_EDGES;
    if (i < N_NODES) {
        if ((i < BATCH) | need1[i]) {
            int p = atomicAdd(n1ctr, 1);
            if (p < CAP1) { idx1[p] = i; map1[i] = p; } else map1[i] = -1;
        } else map1[i] = -1;
    }
}

// ---------------- N3: compact S0 + bucket elist2 by src S1-tile ----------------
// (map1 is final after N2, so bucketing here is race-free.)
__global__ void compact0_bucket(const int* __restrict__ map1, const int* __restrict__ need0,
                                int* __restrict__ idx0, int* __restrict__ map0,
                                int* __restrict__ n0ctr,
                                const int* __restrict__ ei,
                                const int* __restrict__ elist2, const int* __restrict__ ectr2,
                                int* __restrict__ bkt2cnt, int* __restrict__ bkt2) {
    int t = blockIdx.x * blockDim.x + threadIdx.x;
    if (t < N_NODES) {
        if ((map1[t] >= 0) | need0[t]) {
            int p = atomicAdd(n0ctr, 1);
            if (p < CAP0) { idx0[p] = t; map0[t] = p; } else map0[t] = -1;
        } else map0[t] = -1;
        return;
    }
    int j = t - N_NODES;
    int n2 = imin(*ectr2, ECAP2);
    if (j < n2) {
        int e = elist2[j];
        int r = map1[ei[e]];                 // src row in S1 (>=0 by construction)
        if (r >= 0) {
            int tile = r >> 6;
            int p = atomicAdd(&bkt2cnt[tile], 1);
            if (p < BKT2CAP) bkt2[tile * BKT2CAP + p] = e;
        }
    }
}

// ---------------- N5: scatter conv1 messages (grid-stride, capped grid) ----------------
__global__ void scatter_gs(const int* __restrict__ ei, const int* __restrict__ et,
                           const int* __restrict__ elist, const int* __restrict__ ectr, int ecap,
                           const int* __restrict__ mapSrc, const int* __restrict__ mapDst,
                           const float* __restrict__ hsrc,
                           float* __restrict__ Amsg, float* __restrict__ cnt,
                           int cntStride) {
    int n = imin(*ectr, ecap);
    int tot = n * 64;
    int gstr = gridDim.x * blockDim.x;
    for (int g = blockIdx.x * blockDim.x + threadIdx.x; g < tot; g += gstr) {
        int ii = g >> 6, lane = g & 63;
        int e = elist[ii];
        int d = ei[N_EDGES + e];
        int row = mapDst ? mapDst[d] : d;
        if (row < 0) continue;
        int s = mapSrc[ei[e]];
        if (s < 0) continue;
        int r = et[e];
        float4 v = *(const float4*)(hsrc + (size_t)s * HID + lane * 4);
        float* dp = Amsg + (size_t)row * MSGW + (size_t)r * HID + lane * 4;
        atomicAdd(dp + 0, v.x);
        atomicAdd(dp + 1, v.y);
        atomicAdd(dp + 2, v.z);
        atomicAdd(dp + 3, v.w);
        if (lane == 0) atomicAdd(cnt + (size_t)r * cntStride + row, 1.0f);
    }
}

// ---------------- N4: linear1 (unchanged champion) ----------------
__global__ __launch_bounds__(256) void gemm1_mfma(
    const float* __restrict__ x, const int* __restrict__ idx0,
    const unsigned short* __restrict__ w1s, const float* __restrict__ b1,
    float* __restrict__ h0c, const int* __restrict__ Mptr, int Mcap)
{
    int M = imin(*Mptr, Mcap);
    int bm = blockIdx.x * 64;
    if (bm >= M) return;

    __shared__ unsigned short As[64][40];
    __shared__ unsigned short Bs[256][40];

    int tid = threadIdx.x;
    int w = tid >> 6, lane = tid & 63;
    int l16 = lane & 15, lhi = lane >> 4;

    int ar = tid >> 2, ac = tid & 3;
    int gr = idx0[imin(bm + ar, M - 1)];
    const float* aptr = x + (size_t)gr * IN_DIM + ac * 8;

    f32x4 acc[16];
    #pragma unroll
    for (int i = 0; i < 16; i++) acc[i] = (f32x4)0.0f;

    for (int k0 = 0; k0 < IN_DIM; k0 += 32) {
        float4 a0 = *(const float4*)(aptr + k0);
        float4 a1 = *(const float4*)(aptr + k0 + 4);
        unsigned int p0 = (unsigned int)f2bf(a0.x) | ((unsigned int)f2bf(a0.y) << 16);
        unsigned int p1 = (unsigned int)f2bf(a0.z) | ((unsigned int)f2bf(a0.w) << 16);
        unsigned int p2 = (unsigned int)f2bf(a1.x) | ((unsigned int)f2bf(a1.y) << 16);
        unsigned int p3 = (unsigned int)f2bf(a1.z) | ((unsigned int)f2bf(a1.w) << 16);
        *(uint4*)&As[ar][ac * 8] = make_uint4(p0, p1, p2, p3);

        const uint4* bsrc = (const uint4*)(w1s + ((size_t)(k0 >> 5) * 256 + tid) * 32);
        int bswz = (tid >> 3) & 3;
        uint4 b0 = bsrc[0], b1v = bsrc[1], b2 = bsrc[2], b3 = bsrc[3];
        *(uint4*)&Bs[tid][(0 ^ bswz) * 8] = b0;
        *(uint4*)&Bs[tid][(1 ^ bswz) * 8] = b1v;
        *(uint4*)&Bs[tid][(2 ^ bswz) * 8] = b2;
        *(uint4*)&Bs[tid][(3 ^ bswz) * 8] = b3;
        __syncthreads();

        bf16x8 af = *(bf16x8*)&As[w * 16 + l16][lhi * 8];
        #pragma unroll
        for (int f = 0; f < 16; f++) {
            int col = f * 16 + l16;
            bf16x8 bf = *(bf16x8*)&Bs[col][(lhi ^ ((col >> 3) & 3)) * 8];
            acc[f] = __builtin_amdgcn_mfma_f32_16x16x32_bf16(af, bf, acc[f], 0, 0, 0);
        }
        __syncthreads();
    }

    #pragma unroll
    for (int f = 0; f < 16; f++) {
        int col = f * 16 + l16;
        float bb = b1[col];
        #pragma unroll
        for (int reg = 0; reg < 4; reg++) {
            int row = bm + w * 16 + lhi * 4 + reg;
            if (row < M) h0c[(size_t)row * HID + col] = fmaxf(acc[f][reg] + bb, 0.0f);
        }
    }
}

// ---------------- N6: conv1 + fused conv2-message scatter ----------------
// conv part identical to the champion conv_mfma (idx=idx1, map=map0). After
// the K-loop, the 64x256 h1 tile is staged bf16 in LDS (aliased over As/Bs,
// dead by then) and this block's outgoing conv2 edges (bucketed by src tile)
// are scattered from it.
__global__ __launch_bounds__(256) void conv1_scat(
    const float* __restrict__ hsrc,
    const int* __restrict__ idx1, const int* __restrict__ map0,
    const int* __restrict__ map1,
    const float* __restrict__ Amsg, const float* __restrict__ cnt, int cntStride,
    const unsigned short* __restrict__ Bt, const float* __restrict__ bias,
    float* __restrict__ Cout, const int* __restrict__ Mptr, int Mcap,
    const int* __restrict__ ei, const int* __restrict__ et,
    const int* __restrict__ bkt2cnt, const int* __restrict__ bkt2,
    float* __restrict__ Amsg2, float* __restrict__ cnt2)
{
    int M = imin(*Mptr, Mcap);
    int bm = blockIdx.x * 64;
    if (bm >= M) return;

    __shared__ __align__(16) char smem[64 * 264 * 2];   // 33792 B
    unsigned short (*As)[40]   = (unsigned short(*)[40])smem;
    unsigned short (*Bs)[40]   = (unsigned short(*)[40])(smem + 64 * 40 * 2);
    unsigned short (*h1s)[264] = (unsigned short(*)[264])smem;   // aliases As/Bs

    int tid = threadIdx.x;
    int w = tid >> 6, lane = tid & 63;
    int l16 = lane & 15, lhi = lane >> 4;

    int ar = tid >> 2, ac = tid & 3;
    int row = imin(bm + ar, M - 1);
    int node = idx1[row];
    int grow = map0[node]; if (grow < 0) grow = 0;
    const float* rootp = hsrc + (size_t)grow * HID + ac * 8;
    const float* msgp  = Amsg + (size_t)row * MSGW + ac * 8;
    float sc[NREL];
    #pragma unroll
    for (int r = 0; r < NREL; r++)
        sc[r] = 1.0f / fmaxf(cnt[(size_t)r * cntStride + row], 1.0f);

    f32x4 acc[16];
    #pragma unroll
    for (int i = 0; i < 16; i++) acc[i] = (f32x4)0.0f;

    for (int k0 = 0; k0 < KCAT; k0 += 32) {
        float4 a0, a1;
        if (k0 < HID) {
            a0 = *(const float4*)(rootp + k0);
            a1 = *(const float4*)(rootp + k0 + 4);
        } else {
            float s = sc[(k0 - HID) >> 8];
            a0 = *(const float4*)(msgp + (k0 - HID));
            a1 = *(const float4*)(msgp + (k0 - HID) + 4);
            a0.x *= s; a0.y *= s; a0.z *= s; a0.w *= s;
            a1.x *= s; a1.y *= s; a1.z *= s; a1.w *= s;
        }
        unsigned int p0 = (unsigned int)f2bf(a0.x) | ((unsigned int)f2bf(a0.y) << 16);
        unsigned int p1 = (unsigned int)f2bf(a0.z) | ((unsigned int)f2bf(a0.w) << 16);
        unsigned int p2 = (unsigned int)f2bf(a1.x) | ((unsigned int)f2bf(a1.y) << 16);
        unsigned int p3 = (unsigned int)f2bf(a1.z) | ((unsigned int)f2bf(a1.w) << 16);
        *(uint4*)&As[ar][ac * 8] = make_uint4(p0, p1, p2, p3);

        const uint4* bsrc = (const uint4*)(Bt + ((size_t)(k0 >> 5) * 256 + tid) * 32);
        int bswz = (tid >> 3) & 3;
        uint4 b0 = bsrc[0], b1v = bsrc[1], b2v = bsrc[2], b3 = bsrc[3];
        *(uint4*)&Bs[tid][(0 ^ bswz) * 8] = b0;
        *(uint4*)&Bs[tid][(1 ^ bswz) * 8] = b1v;
        *(uint4*)&Bs[tid][(2 ^ bswz) * 8] = b2v;
        *(uint4*)&Bs[tid][(3 ^ bswz) * 8] = b3;
        __syncthreads();

        bf16x8 af = *(bf16x8*)&As[w * 16 + l16][lhi * 8];
        #pragma unroll
        for (int f = 0; f < 16; f++) {
            int col = f * 16 + l16;
            bf16x8 bf = *(bf16x8*)&Bs[col][(lhi ^ ((col >> 3) & 3)) * 8];
            acc[f] = __builtin_amdgcn_mfma_f32_16x16x32_bf16(af, bf, acc[f], 0, 0, 0);
        }
        __syncthreads();   // all LDS reads done -> safe to alias h1s over As/Bs
    }

    // epilogue: write h1c (f32) and stage h1 tile in LDS (bf16)
    #pragma unroll
    for (int f = 0; f < 16; f++) {
        int col = f * 16 + l16;
        float bb = bias[col];
        #pragma unroll
        for (int reg = 0; reg < 4; reg++) {
            int rr = w * 16 + lhi * 4 + reg;
            float v = acc[f][reg] + bb;
            if (bm + rr < M) Cout[(size_t)(bm + rr) * HID + col] = v;
            h1s[rr][col] = f2bf(v);
        }
    }
    __syncthreads();

    // scatter this tile's outgoing conv2 edges from the LDS h1 tile
    int nb = imin(bkt2cnt[blockIdx.x], BKT2CAP);
    for (int ii = w; ii < nb; ii += 4) {           // one wave per edge
        int e = bkt2[blockIdx.x * BKT2CAP + ii];
        int dst = ei[N_EDGES + e];                 // < BATCH
        int r = map1[ei[e]] - bm;                  // 0..63 by bucket construction
        int rel = et[e];
        float v0 = bf2f(h1s[r][lane * 4 + 0]);
        float v1 = bf2f(h1s[r][lane * 4 + 1]);
        float v2 = bf2f(h1s[r][lane * 4 + 2]);
        float v3 = bf2f(h1s[r][lane * 4 + 3]);
        float* dp = Amsg2 + (size_t)dst * MSGW + (size_t)rel * HID + lane * 4;
        atomicAdd(dp + 0, v0);
        atomicAdd(dp + 1, v1);
        atomicAdd(dp + 2, v2);
        atomicAdd(dp + 3, v3);
        if (lane == 0) atomicAdd(&cnt2[(size_t)rel * BATCH + dst], 1.0f);
    }
}

// ---------------- N7: conv2 + lin2 + relu + classifier (unchanged R11) ----------------
__global__ __launch_bounds__(256) void conv2_fused(
    const float* __restrict__ hsrc, const int* __restrict__ map,
    const float* __restrict__ Amsg, const float* __restrict__ cnt,
    const unsigned short* __restrict__ Bt, const float* __restrict__ c2bias,
    const unsigned short* __restrict__ W2t, const float* __restrict__ b2,
    const float* __restrict__ Wc, const float* __restrict__ bc,
    float* __restrict__ out)
{
    int bm = blockIdx.x * 64;

    __shared__ unsigned short As[64][40];
    __shared__ unsigned short Bs[256][40];
    __shared__ unsigned short h2s[64][264];

    int tid = threadIdx.x;
    int w = tid >> 6, lane = tid & 63;
    int l16 = lane & 15, lhi = lane >> 4;

    int ar = tid >> 2, ac = tid & 3;
    int row = bm + ar;
    int grow = map[row]; if (grow < 0) grow = 0;
    const float* rootp = hsrc + (size_t)grow * HID + ac * 8;
    const float* msgp  = Amsg + (size_t)row * MSGW + ac * 8;
    float sc[NREL];
    #pragma unroll
    for (int r = 0; r < NREL; r++)
        sc[r] = 1.0f / fmaxf(cnt[(size_t)r * BATCH + row], 1.0f);

    f32x4 acc[16];
    #pragma unroll
    for (int i = 0; i < 16; i++) acc[i] = (f32x4)0.0f;

    for (int k0 = 0; k0 < KCAT; k0 += 32) {
        float4 a0, a1;
        if (k0 < HID) {
            a0 = *(const float4*)(rootp + k0);
            a1 = *(const float4*)(rootp + k0 + 4);
        } else {
            float s = sc[(k0 - HID) >> 8];
            a0 = *(const float4*)(msgp + (k0 - HID));
            a1 = *(const float4*)(msgp + (k0 - HID) + 4);
            a0.x *= s; a0.y *= s; a0.z *= s; a0.w *= s;
            a1.x *= s; a1.y *= s; a1.z *= s; a1.w *= s;
        }
        unsigned int p0 = (unsigned int)f2bf(a0.x) | ((unsigned int)f2bf(a0.y) << 16);
        unsigned int p1 = (unsigned int)f2bf(a0.z) | ((unsigned int)f2bf(a0.w) << 16);
        unsigned int p2 = (unsigned int)f2bf(a1.x) | ((unsigned int)f2bf(a1.y) << 16);
        unsigned int p3 = (unsigned int)f2bf(a1.z) | ((unsigned int)f2bf(a1.w) << 16);
        *(uint4*)&As[ar][ac * 8] = make_uint4(p0, p1, p2, p3);

        const uint4* bsrc = (const uint4*)(Bt + ((size_t)(k0 >> 5) * 256 + tid) * 32);
        int bswz = (tid >> 3) & 3;
        uint4 b0 = bsrc[0], b1v = bsrc[1], b2v = bsrc[2], b3 = bsrc[3];
        *(uint4*)&Bs[tid][(0 ^ bswz) * 8] = b0;
        *(uint4*)&Bs[tid][(1 ^ bswz) * 8] = b1v;
        *(uint4*)&Bs[tid][(2 ^ bswz) * 8] = b2v;
        *(uint4*)&Bs[tid][(3 ^ bswz) * 8] = b3;
        __syncthreads();

        bf16x8 af = *(bf16x8*)&As[w * 16 + l16][lhi * 8];
        #pragma unroll
        for (int f = 0; f < 16; f++) {
            int col = f * 16 + l16;
            bf16x8 bf = *(bf16x8*)&Bs[col][(lhi ^ ((col >> 3) & 3)) * 8];
            acc[f] = __builtin_amdgcn_mfma_f32_16x16x32_bf16(af, bf, acc[f], 0, 0, 0);
        }
        __syncthreads();
    }

    #pragma unroll
    for (int f = 0; f < 16; f++) {
        int col = f * 16 + l16;
        float bb = c2bias[col];
        #pragma unroll
        for (int reg = 0; reg < 4; reg++)
            h2s[w * 16 + lhi * 4 + reg][col] = f2bf(acc[f][reg] + bb);
    }
    __syncthreads();

    f32x4 acc2[8];
    #pragma unroll
    for (int i = 0; i < 8; i++) acc2[i] = (f32x4)0.0f;
    for (int s = 0; s < 8; s++) {
        bf16x8 af = *(bf16x8*)&h2s[w * 16 + l16][s * 32 + lhi * 8];
        #pragma unroll
        for (int f = 0; f < 8; f++) {
            bf16x8 bf = *(const bf16x8*)(W2t + ((size_t)(s * 8 + f) * 64 + lane) * 8);
            acc2[f] = __builtin_amdgcn_mfma_f32_16x16x32_bf16(af, bf, acc2[f], 0, 0, 0);
        }
    }

    float p0[4] = {0.f, 0.f, 0.f, 0.f}, p1[4] = {0.f, 0.f, 0.f, 0.f};
    #pragma unroll
    for (int f = 0; f < 8; f++) {
        int col = f * 16 + l16;
        float w0 = Wc[col * 2 + 0], w1 = Wc[col * 2 + 1];
        float bb = b2[col];
        #pragma unroll
        for (int reg = 0; reg < 4; reg++) {
            float h = fmaxf(acc2[f][reg] + bb, 0.0f);
            p0[reg] += h * w0;
            p1[reg] += h * w1;
        }
    }
    #pragma unroll
    for (int o = 1; o <= 8; o <<= 1) {
        #pragma unroll
        for (int reg = 0; reg < 4; reg++) {
            p0[reg] += __shfl_xor(p0[reg], o);
            p1[reg] += __shfl_xor(p1[reg], o);
        }
    }
    if (l16 == 0) {
        #pragma unroll
        for (int reg = 0; reg < 4; reg++) {
            int r = bm + w * 16 + lhi * 4 + reg;
            out[r * 2 + 0] = p0[reg] + bc[0];
            out[r * 2 + 1] = p1[reg] + bc[1];
        }
    }
}

// ---------------- host ----------------

extern "C" void kernel_launch(void* const* d_in, const int* in_sizes, int n_in,
                              void* d_out, int out_size, void* d_ws, size_t ws_size,
                              hipStream_t stream) {
    const float* x      = (const float*)d_in[0];
    const int*   ei     = (const int*)d_in[1];
    const int*   et     = (const int*)d_in[2];
    const float* W1     = (const float*)d_in[4];
    const float* b1     = (const float*)d_in[5];
    const float* c1W    = (const float*)d_in[6];
    const float* c1root = (const float*)d_in[7];
    const float* c1bias = (const float*)d_in[8];
    const float* c2W    = (const float*)d_in[9];
    const float* c2root = (const float*)d_in[10];
    const float* c2bias = (const float*)d_in[11];
    const float* W2     = (const float*)d_in[12];
    const float* b2     = (const float*)d_in[13];
    const float* Wc     = (const float*)d_in[14];
    const float* bc     = (const float*)d_in[15];
    float* out = (float*)d_out;

    char* ws = (char*)d_ws;
    size_t off = 0;
    auto alloc = [&](size_t bytes) -> char* {
        char* p = ws + off;
        off = (off + bytes + 255) & ~(size_t)255;
        return p;
    };

    // --- memset region (N0): ctrs | bkt2cnt | cnt1 | cnt2 | need1 | need0 ---
    size_t zb_ctr  = 16;
    size_t zb_bkt  = (size_t)NTILE1 * 4;
    size_t zb_cnt1 = (size_t)NREL * CAP1 * 4;
    size_t zb_cnt2 = (size_t)NREL * BATCH * 4;
    size_t zb_need = (size_t)N_NODES * 4;
    size_t msbytes = zb_ctr + zb_bkt + zb_cnt1 + zb_cnt2 + 2 * zb_need;
    char* zsmall = alloc(msbytes);
    int*   n1ctr   = (int*)zsmall;
    int*   n0ctr   = n1ctr + 1;
    int*   ectr1   = n1ctr + 2;
    int*   ectr2   = n1ctr + 3;
    int*   bkt2cnt = (int*)(zsmall + zb_ctr);
    float* cnt1    = (float*)(zsmall + zb_ctr + zb_bkt);
    float* cnt2    = (float*)(zsmall + zb_ctr + zb_bkt + zb_cnt1);
    int*   need1   = (int*)(zsmall + zb_ctr + zb_bkt + zb_cnt1 + zb_cnt2);
    int*   need0   = (int*)((char*)need1 + zb_need);

    // --- Amsg region (zeroed in N1) ---
    size_t zb_amsg1 = (size_t)CAP1 * MSGW * 4;
    size_t zb_amsg2 = (size_t)BATCH * MSGW * 4;
    char* amsg = alloc(zb_amsg1 + zb_amsg2);
    float* Amsg1 = (float*)amsg;
    float* Amsg2 = (float*)(amsg + zb_amsg1);
    int nzA2 = (int)((zb_amsg1 + zb_amsg2) / 32);   // 32 B per zero thread

    int* map1  = (int*)alloc(N_NODES * 4);
    int* map0  = (int*)alloc(N_NODES * 4);
    int* idx1  = (int*)alloc(CAP1 * 4);
    int* idx0  = (int*)alloc(CAP0 * 4);
    int* elist1 = (int*)alloc(ECAP1 * 4);
    int* elist2 = (int*)alloc(ECAP2 * 4);
    int* bkt2   = (int*)alloc((size_t)NTILE1 * BKT2CAP * 4);   // 256 KB
    float* h0c = (float*)alloc((size_t)CAP0 * HID * 4);
    float* h1c = (float*)alloc((size_t)CAP1 * HID * 4);
    unsigned short* w1s = (unsigned short*)alloc((size_t)IN_DIM * HID * 2);
    unsigned short* B1s = (unsigned short*)alloc((size_t)KCAT * HID * 2);
    unsigned short* B2s = (unsigned short*)alloc((size_t)KCAT * HID * 2);
    unsigned short* W2t = (unsigned short*)alloc((size_t)HID * OUT_DIM * 2);
    (void)ws_size; (void)in_sizes; (void)n_in; (void)out_size;

    const int NB = 256;

    // N0: zero flags/counters/cnts/buckets
    hipMemsetAsync(zsmall, 0, msbytes, stream);
    // N1: Amsg zero + weight prep + mark1c
    int n1_total = nzA2 + P1n + 2 * P2n + PW2n + N_EDGES;
    prep_mark1<<<dim3((n1_total + NB - 1) / NB), NB, 0, stream>>>(
        (uint4*)amsg, nzA2, W1, c1root, c1W, c2root, c2W, W2,
        w1s, B1s, B2s, W2t, ei, need1, elist2, ectr2);
    // N2: mark0c + compact S1
    int n2_total = N_EDGES + N_NODES;
    mark0_compact1<<<dim3((n2_total + NB - 1) / NB), NB, 0, stream>>>(
        ei, need1, need0, elist1, ectr1, idx1, map1, n1ctr);
    // N3: compact S0 + bucket conv2 edges by src tile
    int n3_total = N_NODES + ECAP2;
    compact0_bucket<<<dim3((n3_total + NB - 1) / NB), NB, 0, stream>>>(
        map1, need0, idx0, map0, n0ctr, ei, elist2, ectr2, bkt2cnt, bkt2);
    // N4: h0c = relu(x[S0] @ W1 + b1)
    gemm1_mfma<<<dim3(CAP0 / 64), NB, 0, stream>>>(x, idx0, w1s, b1, h0c, n0ctr, CAP0);
    // N5: scatter conv1 messages (grid-stride, 2048 blocks)
    scatter_gs<<<dim3(2048), NB, 0, stream>>>(ei, et, elist1, ectr1, ECAP1,
                                              map0, map1, h0c, Amsg1, cnt1, CAP1);
    // N6: conv1 + fused conv2-message scatter
    conv1_scat<<<dim3(CAP1 / 64), NB, 0, stream>>>(
        h0c, idx1, map0, map1, Amsg1, cnt1, CAP1, B1s, c1bias, h1c, n1ctr, CAP1,
        ei, et, bkt2cnt, bkt2, Amsg2, cnt2);
    // N7: conv2 + lin2 + relu + classifier
    conv2_fused<<<dim3(BATCH / 64), NB, 0, stream>>>(h1c, map1, Amsg2, cnt2,
                                                     B2s, c2bias, W2t, b2, Wc, bc, out);
}

// Round 13
// 384.867 us; speedup vs baseline: 1.0014x; 1.0014x over previous
//
#include <hip/hip_runtime.h>

// RGCN pruned to the 2-hop cone of the first 1024 nodes.
// R12: 8 graph nodes. scatter2 fused into conv1's epilogue (edges bucketed
// by src S1-tile in compact0; conv1 scatters from LDS-staged bf16 h1 tile,
// aliased over dead As/Bs). scatter1 grid-stride capped at 2048 blocks.
// prep zero at 32B/thread. R11 measured 379.4us @ absmax 1.95e-3.

#define N_NODES 100000
#define N_EDGES 400000
#define IN_DIM  768
#define HID     256
#define OUT_DIM 128
#define NREL    3
#define BATCH   1024
#define KCAT    1024   // HID*(NREL+1)
#define MSGW    768    // NREL*HID
#define CAP0    32768  // |S0| ~23K
#define CAP1    8192   // |S1| ~5K
#define ECAP1   32768  // edges into S1 ~20K
#define ECAP2   8192   // edges into S2 ~4.1K
#define NTILE1  (CAP1 / 64)   // 128 S1 tiles
#define BKT2CAP 512           // edges per tile bucket (expected ~51)

typedef __attribute__((ext_vector_type(8))) short bf16x8;
typedef __attribute__((ext_vector_type(4))) float f32x4;

static __device__ __forceinline__ int imin(int a, int b) { return a < b ? a : b; }

static __device__ __forceinline__ unsigned short f2bf(float f) {
    union { float f; unsigned int u; } v; v.f = f;
    unsigned int r = v.u + 0x7FFFu + ((v.u >> 16) & 1u);   // RNE
    return (unsigned short)(r >> 16);
}

static __device__ __forceinline__ float bf2f(unsigned short h) {
    union { unsigned int u; float f; } c; c.u = ((unsigned int)h) << 16;
    return c.f;
}

#define P1n  ((IN_DIM * HID) / 8)    // 24576 w1s threads
#define P2n  ((KCAT * HID) / 8)      // 32768 per B1s/B2s
#define PW2n ((HID * OUT_DIM) / 8)   // 4096 W2t threads

// ---------------- N1: Amsg zero (32B/thread) + weight prep + mark1c ----------------
__global__ __launch_bounds__(256) void prep_mark1(
    uint4* __restrict__ zp, int nzA2,
    const float* __restrict__ W1,
    const float* __restrict__ c1root, const float* __restrict__ c1W,
    const float* __restrict__ c2root, const float* __restrict__ c2W,
    const float* __restrict__ W2,
    unsigned short* __restrict__ w1s,
    unsigned short* __restrict__ B1s,
    unsigned short* __restrict__ B2s,
    unsigned short* __restrict__ W2t,
    const int* __restrict__ ei, int* __restrict__ need1,
    int* __restrict__ elist2, int* __restrict__ ectr2)
{
    int t = blockIdx.x * blockDim.x + threadIdx.x;
    if (t < nzA2) {
        uint4 z = make_uint4(0u, 0u, 0u, 0u);
        zp[2 * t] = z;
        zp[2 * t + 1] = z;
        return;
    }
    int u = t - nzA2;
    if (u < P1n) {
        int base = u * 8;
        int j0 = base & 31, c = (base >> 5) & 255, s = base >> 13;
        unsigned int pk[4];
        #pragma unroll
        for (int q = 0; q < 4; q++) {
            unsigned short lo = f2bf(W1[((s * 32 + j0 + 2 * q) << 8) + c]);
            unsigned short hi = f2bf(W1[((s * 32 + j0 + 2 * q + 1) << 8) + c]);
            pk[q] = (unsigned int)lo | ((unsigned int)hi << 16);
        }
        *(uint4*)&w1s[base] = make_uint4(pk[0], pk[1], pk[2], pk[3]);
        return;
    }
    u -= P1n;
    if (u < 2 * P2n) {
        int which2 = u >= P2n;
        const float* root = which2 ? c2root : c1root;
        const float* Wr   = which2 ? c2W : c1W;
        unsigned short* dst = which2 ? B2s : B1s;
        int base = (u - (which2 ? P2n : 0)) * 8;
        int j0 = base & 31, c = (base >> 5) & 255, s = base >> 13;
        int k0 = s * 32 + j0;
        unsigned int pk[4];
        #pragma unroll
        for (int q = 0; q < 4; q++) {
            int ka = k0 + 2 * q, kb = ka + 1;
            float va = (ka < HID) ? root[(ka << 8) + c] : Wr[((ka - HID) << 8) + c];
            float vb = (kb < HID) ? root[(kb << 8) + c] : Wr[((kb - HID) << 8) + c];
            pk[q] = (unsigned int)f2bf(va) | ((unsigned int)f2bf(vb) << 16);
        }
        *(uint4*)&dst[base] = make_uint4(pk[0], pk[1], pk[2], pk[3]);
        return;
    }
    u -= 2 * P2n;
    if (u < PW2n) {
        int s = u >> 9, f = (u >> 6) & 7, l = u & 63;
        int kb = s * 32 + ((l >> 4) << 3);
        int c  = (f << 4) + (l & 15);
        unsigned int pk[4];
        #pragma unroll
        for (int q = 0; q < 4; q++) {
            unsigned short lo = f2bf(W2[(size_t)(kb + 2 * q)     * OUT_DIM + c]);
            unsigned short hi = f2bf(W2[(size_t)(kb + 2 * q + 1) * OUT_DIM + c]);
            pk[q] = (unsigned int)lo | ((unsigned int)hi << 16);
        }
        *(uint4*)&W2t[(size_t)u * 8] = make_uint4(pk[0], pk[1], pk[2], pk[3]);
        return;
    }
    u -= PW2n;
    if (u < N_EDGES) {
        if (ei[N_EDGES + u] < BATCH) {
            need1[ei[u]] = 1;   // benign same-value race
            int p = atomicAdd(ectr2, 1);
            if (p < ECAP2) elist2[p] = u;
        }
    }
}

// ---------------- N2: mark0c + compact S1 ----------------
__global__ void mark0_compact1(const int* __restrict__ ei, const int* __restrict__ need1,
                               int* __restrict__ need0,
                               int* __restrict__ elist1, int* __restrict__ ectr1,
                               int* __restrict__ idx1, int* __restrict__ map1,
                               int* __restrict__ n1ctr) {
    int t = blockIdx.x * blockDim.x + threadIdx.x;
    if (t < N_EDGES) {
        int d = ei[N_EDGES + t];
        if (d < BATCH || need1[d]) {
            need0[ei[t]] = 1;
            int p = atomicAdd(ectr1, 1);
            if (p < ECAP1) elist1[p] = t;
        }
        return;
    }
    int i = t - N_EDGES;
    if (i < N_NODES) {
        if ((i < BATCH) | need1[i]) {
            int p = atomicAdd(n1ctr, 1);
            if (p < CAP1) { idx1[p] = i; map1[i] = p; } else map1[i] = -1;
        } else map1[i] = -1;
    }
}

// ---------------- N3: compact S0 + bucket elist2 by src S1-tile ----------------
// (map1 is final after N2, so bucketing here is race-free.)
__global__ void compact0_bucket(const int* __restrict__ map1, const int* __restrict__ need0,
                                int* __restrict__ idx0, int* __restrict__ map0,
                                int* __restrict__ n0ctr,
                                const int* __restrict__ ei,
                                const int* __restrict__ elist2, const int* __restrict__ ectr2,
                                int* __restrict__ bkt2cnt, int* __restrict__ bkt2) {
    int t = blockIdx.x * blockDim.x + threadIdx.x;
    if (t < N_NODES) {
        if ((map1[t] >= 0) | need0[t]) {
            int p = atomicAdd(n0ctr, 1);
            if (p < CAP0) { idx0[p] = t; map0[t] = p; } else map0[t] = -1;
        } else map0[t] = -1;
        return;
    }
    int j = t - N_NODES;
    int n2 = imin(*ectr2, ECAP2);
    if (j < n2) {
        int e = elist2[j];
        int r = map1[ei[e]];                 // src row in S1 (>=0 by construction)
        if (r >= 0) {
            int tile = r >> 6;
            int p = atomicAdd(&bkt2cnt[tile], 1);
            if (p < BKT2CAP) bkt2[tile * BKT2CAP + p] = e;
        }
    }
}

// ---------------- N5: scatter conv1 messages (grid-stride, capped grid) ----------------
__global__ void scatter_gs(const int* __restrict__ ei, const int* __restrict__ et,
                           const int* __restrict__ elist, const int* __restrict__ ectr, int ecap,
                           const int* __restrict__ mapSrc, const int* __restrict__ mapDst,
                           const float* __restrict__ hsrc,
                           float* __restrict__ Amsg, float* __restrict__ cnt,
                           int cntStride) {
    int n = imin(*ectr, ecap);
    int tot = n * 64;
    int gstr = gridDim.x * blockDim.x;
    for (int g = blockIdx.x * blockDim.x + threadIdx.x; g < tot; g += gstr) {
        int ii = g >> 6, lane = g & 63;
        int e = elist[ii];
        int d = ei[N_EDGES + e];
        int row = mapDst ? mapDst[d] : d;
        if (row < 0) continue;
        int s = mapSrc[ei[e]];
        if (s < 0) continue;
        int r = et[e];
        float4 v = *(const float4*)(hsrc + (size_t)s * HID + lane * 4);
        float* dp = Amsg + (size_t)row * MSGW + (size_t)r * HID + lane * 4;
        atomicAdd(dp + 0, v.x);
        atomicAdd(dp + 1, v.y);
        atomicAdd(dp + 2, v.z);
        atomicAdd(dp + 3, v.w);
        if (lane == 0) atomicAdd(cnt + (size_t)r * cntStride + row, 1.0f);
    }
}

// ---------------- N4: linear1 (unchanged champion) ----------------
__global__ __launch_bounds__(256) void gemm1_mfma(
    const float* __restrict__ x, const int* __restrict__ idx0,
    const unsigned short* __restrict__ w1s, const float* __restrict__ b1,
    float* __restrict__ h0c, const int* __restrict__ Mptr, int Mcap)
{
    int M = imin(*Mptr, Mcap);
    int bm = blockIdx.x * 64;
    if (bm >= M) return;

    __shared__ unsigned short As[64][40];
    __shared__ unsigned short Bs[256][40];

    int tid = threadIdx.x;
    int w = tid >> 6, lane = tid & 63;
    int l16 = lane & 15, lhi = lane >> 4;

    int ar = tid >> 2, ac = tid & 3;
    int gr = idx0[imin(bm + ar, M - 1)];
    const float* aptr = x + (size_t)gr * IN_DIM + ac * 8;

    f32x4 acc[16];
    #pragma unroll
    for (int i = 0; i < 16; i++) acc[i] = (f32x4)0.0f;

    for (int k0 = 0; k0 < IN_DIM; k0 += 32) {
        float4 a0 = *(const float4*)(aptr + k0);
        float4 a1 = *(const float4*)(aptr + k0 + 4);
        unsigned int p0 = (unsigned int)f2bf(a0.x) | ((unsigned int)f2bf(a0.y) << 16);
        unsigned int p1 = (unsigned int)f2bf(a0.z) | ((unsigned int)f2bf(a0.w) << 16);
        unsigned int p2 = (unsigned int)f2bf(a1.x) | ((unsigned int)f2bf(a1.y) << 16);
        unsigned int p3 = (unsigned int)f2bf(a1.z) | ((unsigned int)f2bf(a1.w) << 16);
        *(uint4*)&As[ar][ac * 8] = make_uint4(p0, p1, p2, p3);

        const uint4* bsrc = (const uint4*)(w1s + ((size_t)(k0 >> 5) * 256 + tid) * 32);
        int bswz = (tid >> 3) & 3;
        uint4 b0 = bsrc[0], b1v = bsrc[1], b2 = bsrc[2], b3 = bsrc[3];
        *(uint4*)&Bs[tid][(0 ^ bswz) * 8] = b0;
        *(uint4*)&Bs[tid][(1 ^ bswz) * 8] = b1v;
        *(uint4*)&Bs[tid][(2 ^ bswz) * 8] = b2;
        *(uint4*)&Bs[tid][(3 ^ bswz) * 8] = b3;
        __syncthreads();

        bf16x8 af = *(bf16x8*)&As[w * 16 + l16][lhi * 8];
        #pragma unroll
        for (int f = 0; f < 16; f++) {
            int col = f * 16 + l16;
            bf16x8 bf = *(bf16x8*)&Bs[col][(lhi ^ ((col >> 3) & 3)) * 8];
            acc[f] = __builtin_amdgcn_mfma_f32_16x16x32_bf16(af, bf, acc[f], 0, 0, 0);
        }
        __syncthreads();
    }

    #pragma unroll
    for (int f = 0; f < 16; f++) {
        int col = f * 16 + l16;
        float bb = b1[col];
        #pragma unroll
        for (int reg = 0; reg < 4; reg++) {
            int row = bm + w * 16 + lhi * 4 + reg;
            if (row < M) h0c[(size_t)row * HID + col] = fmaxf(acc[f][reg] + bb, 0.0f);
        }
    }
}

// ---------------- N6: conv1 + fused conv2-message scatter ----------------
// conv part identical to the champion conv_mfma (idx=idx1, map=map0). After
// the K-loop, the 64x256 h1 tile is staged bf16 in LDS (aliased over As/Bs,
// dead by then) and this block's outgoing conv2 edges (bucketed by src tile)
// are scattered from it.
__global__ __launch_bounds__(256) void conv1_scat(
    const float* __restrict__ hsrc,
    const int* __restrict__ idx1, const int* __restrict__ map0,
    const int* __restrict__ map1,
    const float* __restrict__ Amsg, const float* __restrict__ cnt, int cntStride,
    const unsigned short* __restrict__ Bt, const float* __restrict__ bias,
    float* __restrict__ Cout, const int* __restrict__ Mptr, int Mcap,
    const int* __restrict__ ei, const int* __restrict__ et,
    const int* __restrict__ bkt2cnt, const int* __restrict__ bkt2,
    float* __restrict__ Amsg2, float* __restrict__ cnt2)
{
    int M = imin(*Mptr, Mcap);
    int bm = blockIdx.x * 64;
    if (bm >= M) return;

    __shared__ __align__(16) char smem[64 * 264 * 2];   // 33792 B
    unsigned short (*As)[40]   = (unsigned short(*)[40])smem;
    unsigned short (*Bs)[40]   = (unsigned short(*)[40])(smem + 64 * 40 * 2);
    unsigned short (*h1s)[264] = (unsigned short(*)[264])smem;   // aliases As/Bs

    int tid = threadIdx.x;
    int w = tid >> 6, lane = tid & 63;
    int l16 = lane & 15, lhi = lane >> 4;

    int ar = tid >> 2, ac = tid & 3;
    int row = imin(bm + ar, M - 1);
    int node = idx1[row];
    int grow = map0[node]; if (grow < 0) grow = 0;
    const float* rootp = hsrc + (size_t)grow * HID + ac * 8;
    const float* msgp  = Amsg + (size_t)row * MSGW + ac * 8;
    float sc[NREL];
    #pragma unroll
    for (int r = 0; r < NREL; r++)
        sc[r] = 1.0f / fmaxf(cnt[(size_t)r * cntStride + row], 1.0f);

    f32x4 acc[16];
    #pragma unroll
    for (int i = 0; i < 16; i++) acc[i] = (f32x4)0.0f;

    for (int k0 = 0; k0 < KCAT; k0 += 32) {
        float4 a0, a1;
        if (k0 < HID) {
            a0 = *(const float4*)(rootp + k0);
            a1 = *(const float4*)(rootp + k0 + 4);
        } else {
            float s = sc[(k0 - HID) >> 8];
            a0 = *(const float4*)(msgp + (k0 - HID));
            a1 = *(const float4*)(msgp + (k0 - HID) + 4);
            a0.x *= s; a0.y *= s; a0.z *= s; a0.w *= s;
            a1.x *= s; a1.y *= s; a1.z *= s; a1.w *= s;
        }
        unsigned int p0 = (unsigned int)f2bf(a0.x) | ((unsigned int)f2bf(a0.y) << 16);
        unsigned int p1 = (unsigned int)f2bf(a0.z) | ((unsigned int)f2bf(a0.w) << 16);
        unsigned int p2 = (unsigned int)f2bf(a1.x) | ((unsigned int)f2bf(a1.y) << 16);
        unsigned int p3 = (unsigned int)f2bf(a1.z) | ((unsigned int)f2bf(a1.w) << 16);
        *(uint4*)&As[ar][ac * 8] = make_uint4(p0, p1, p2, p3);

        const uint4* bsrc = (const uint4*)(Bt + ((size_t)(k0 >> 5) * 256 + tid) * 32);
        int bswz = (tid >> 3) & 3;
        uint4 b0 = bsrc[0], b1v = bsrc[1], b2v = bsrc[2], b3 = bsrc[3];
        *(uint4*)&Bs[tid][(0 ^ bswz) * 8] = b0;
        *(uint4*)&Bs[tid][(1 ^ bswz) * 8] = b1v;
        *(uint4*)&Bs[tid][(2 ^ bswz) * 8] = b2v;
        *(uint4*)&Bs[tid][(3 ^ bswz) * 8] = b3;
        __syncthreads();

        bf16x8 af = *(bf16x8*)&As[w * 16 + l16][lhi * 8];
        #pragma unroll
        for (int f = 0; f < 16; f++) {
            int col = f * 16 + l16;
            bf16x8 bf = *(bf16x8*)&Bs[col][(lhi ^ ((col >> 3) & 3)) * 8];
            acc[f] = __builtin_amdgcn_mfma_f32_16x16x32_bf16(af, bf, acc[f], 0, 0, 0);
        }
        __syncthreads();   // all LDS reads done -> safe to alias h1s over As/Bs
    }

    // epilogue: write h1c (f32) and stage h1 tile in LDS (bf16)
    #pragma unroll
    for (int f = 0; f < 16; f++) {
        int col = f * 16 + l16;
        float bb = bias[col];
        #pragma unroll
        for (int reg = 0; reg < 4; reg++) {
            int rr = w * 16 + lhi * 4 + reg;
            float v = acc[f][reg] + bb;
            if (bm + rr < M) Cout[(size_t)(bm + rr) * HID + col] = v;
            h1s[rr][col] = f2bf(v);
        }
    }
    __syncthreads();

    // scatter this tile's outgoing conv2 edges from the LDS h1 tile
    int nb = imin(bkt2cnt[blockIdx.x], BKT2CAP);
    for (int ii = w; ii < nb; ii += 4) {           // one wave per edge
        int e = bkt2[blockIdx.x * BKT2CAP + ii];
        int dst = ei[N_EDGES + e];                 // < BATCH
        int r = map1[ei[e]] - bm;                  // 0..63 by bucket construction
        int rel = et[e];
        float v0 = bf2f(h1s[r][lane * 4 + 0]);
        float v1 = bf2f(h1s[r][lane * 4 + 1]);
        float v2 = bf2f(h1s[r][lane * 4 + 2]);
        float v3 = bf2f(h1s[r][lane * 4 + 3]);
        float* dp = Amsg2 + (size_t)dst * MSGW + (size_t)rel * HID + lane * 4;
        atomicAdd(dp + 0, v0);
        atomicAdd(dp + 1, v1);
        atomicAdd(dp + 2, v2);
        atomicAdd(dp + 3, v3);
        if (lane == 0) atomicAdd(&cnt2[(size_t)rel * BATCH + dst], 1.0f);
    }
}

// ---------------- N7: conv2 + lin2 + relu + classifier (unchanged R11) ----------------
__global__ __launch_bounds__(256) void conv2_fused(
    const float* __restrict__ hsrc, const int* __restrict__ map,
    const float* __restrict__ Amsg, const float* __restrict__ cnt,
    const unsigned short* __restrict__ Bt, const float* __restrict__ c2bias,
    const unsigned short* __restrict__ W2t, const float* __restrict__ b2,
    const float* __restrict__ Wc, const float* __restrict__ bc,
    float* __restrict__ out)
{
    int bm = blockIdx.x * 64;

    __shared__ unsigned short As[64][40];
    __shared__ unsigned short Bs[256][40];
    __shared__ unsigned short h2s[64][264];

    int tid = threadIdx.x;
    int w = tid >> 6, lane = tid & 63;
    int l16 = lane & 15, lhi = lane >> 4;

    int ar = tid >> 2, ac = tid & 3;
    int row = bm + ar;
    int grow = map[row]; if (grow < 0) grow = 0;
    const float* rootp = hsrc + (size_t)grow * HID + ac * 8;
    const float* msgp  = Amsg + (size_t)row * MSGW + ac * 8;
    float sc[NREL];
    #pragma unroll
    for (int r = 0; r < NREL; r++)
        sc[r] = 1.0f / fmaxf(cnt[(size_t)r * BATCH + row], 1.0f);

    f32x4 acc[16];
    #pragma unroll
    for (int i = 0; i < 16; i++) acc[i] = (f32x4)0.0f;

    for (int k0 = 0; k0 < KCAT; k0 += 32) {
        float4 a0, a1;
        if (k0 < HID) {
            a0 = *(const float4*)(rootp + k0);
            a1 = *(const float4*)(rootp + k0 + 4);
        } else {
            float s = sc[(k0 - HID) >> 8];
            a0 = *(const float4*)(msgp + (k0 - HID));
            a1 = *(const float4*)(msgp + (k0 - HID) + 4);
            a0.x *= s; a0.y *= s; a0.z *= s; a0.w *= s;
            a1.x *= s; a1.y *= s; a1.z *= s; a1.w *= s;
        }
        unsigned int p0 = (unsigned int)f2bf(a0.x) | ((unsigned int)f2bf(a0.y) << 16);
        unsigned int p1 = (unsigned int)f2bf(a0.z) | ((unsigned int)f2bf(a0.w) << 16);
        unsigned int p2 = (unsigned int)f2bf(a1.x) | ((unsigned int)f2bf(a1.y) << 16);
        unsigned int p3 = (unsigned int)f2bf(a1.z) | ((unsigned int)f2bf(a1.w) << 16);
        *(uint4*)&As[ar][ac * 8] = make_uint4(p0, p1, p2, p3);

        const uint4* bsrc = (const uint4*)(Bt + ((size_t)(k0 >> 5) * 256 + tid) * 32);
        int bswz = (tid >> 3) & 3;
        uint4 b0 = bsrc[0], b1v = bsrc[1], b2v = bsrc[2], b3 = bsrc[3];
        *(uint4*)&Bs[tid][(0 ^ bswz) * 8] = b0;
        *(uint4*)&Bs[tid][(1 ^ bswz) * 8] = b1v;
        *(uint4*)&Bs[tid][(2 ^ bswz) * 8] = b2v;
        *(uint4*)&Bs[tid][(3 ^ bswz) * 8] = b3;
        __syncthreads();

        bf16x8 af = *(bf16x8*)&As[w * 16 + l16][lhi * 8];
        #pragma unroll
        for (int f = 0; f < 16; f++) {
            int col = f * 16 + l16;
            bf16x8 bf = *(bf16x8*)&Bs[col][(lhi ^ ((col >> 3) & 3)) * 8];
            acc[f] = __builtin_amdgcn_mfma_f32_16x16x32_bf16(af, bf, acc[f], 0, 0, 0);
        }
        __syncthreads();
    }

    #pragma unroll
    for (int f = 0; f < 16; f++) {
        int col = f * 16 + l16;
        float bb = c2bias[col];
        #pragma unroll
        for (int reg = 0; reg < 4; reg++)
            h2s[w * 16 + lhi * 4 + reg][col] = f2bf(acc[f][reg] + bb);
    }
    __syncthreads();

    f32x4 acc2[8];
    #pragma unroll
    for (int i = 0; i < 8; i++) acc2[i] = (f32x4)0.0f;
    for (int s = 0; s < 8; s++) {
        bf16x8 af = *(bf16x8*)&h2s[w * 16 + l16][s * 32 + lhi * 8];
        #pragma unroll
        for (int f = 0; f < 8; f++) {
            bf16x8 bf = *(const bf16x8*)(W2t + ((size_t)(s * 8 + f) * 64 + lane) * 8);
            acc2[f] = __builtin_amdgcn_mfma_f32_16x16x32_bf16(af, bf, acc2[f], 0, 0, 0);
        }
    }

    float p0[4] = {0.f, 0.f, 0.f, 0.f}, p1[4] = {0.f, 0.f, 0.f, 0.f};
    #pragma unroll
    for (int f = 0; f < 8; f++) {
        int col = f * 16 + l16;
        float w0 = Wc[col * 2 + 0], w1 = Wc[col * 2 + 1];
        float bb = b2[col];
        #pragma unroll
        for (int reg = 0; reg < 4; reg++) {
            float h = fmaxf(acc2[f][reg] + bb, 0.0f);
            p0[reg] += h * w0;
            p1[reg] += h * w1;
        }
    }
    #pragma unroll
    for (int o = 1; o <= 8; o <<= 1) {
        #pragma unroll
        for (int reg = 0; reg < 4; reg++) {
            p0[reg] += __shfl_xor(p0[reg], o);
            p1[reg] += __shfl_xor(p1[reg], o);
        }
    }
    if (l16 == 0) {
        #pragma unroll
        for (int reg = 0; reg < 4; reg++) {
            int r = bm + w * 16 + lhi * 4 + reg;
            out[r * 2 + 0] = p0[reg] + bc[0];
            out[r * 2 + 1] = p1[reg] + bc[1];
        }
    }
}

// ---------------- host ----------------

extern "C" void kernel_launch(void* const* d_in, const int* in_sizes, int n_in,
                              void* d_out, int out_size, void* d_ws, size_t ws_size,
                              hipStream_t stream) {
    const float* x      = (const float*)d_in[0];
    const int*   ei     = (const int*)d_in[1];
    const int*   et     = (const int*)d_in[2];
    const float* W1     = (const float*)d_in[4];
    const float* b1     = (const float*)d_in[5];
    const float* c1W    = (const float*)d_in[6];
    const float* c1root = (const float*)d_in[7];
    const float* c1bias = (const float*)d_in[8];
    const float* c2W    = (const float*)d_in[9];
    const float* c2root = (const float*)d_in[10];
    const float* c2bias = (const float*)d_in[11];
    const float* W2     = (const float*)d_in[12];
    const float* b2     = (const float*)d_in[13];
    const float* Wc     = (const float*)d_in[14];
    const float* bc     = (const float*)d_in[15];
    float* out = (float*)d_out;

    char* ws = (char*)d_ws;
    size_t off = 0;
    auto alloc = [&](size_t bytes) -> char* {
        char* p = ws + off;
        off = (off + bytes + 255) & ~(size_t)255;
        return p;
    };

    // --- memset region (N0): ctrs | bkt2cnt | cnt1 | cnt2 | need1 | need0 ---
    size_t zb_ctr  = 16;
    size_t zb_bkt  = (size_t)NTILE1 * 4;
    size_t zb_cnt1 = (size_t)NREL * CAP1 * 4;
    size_t zb_cnt2 = (size_t)NREL * BATCH * 4;
    size_t zb_need = (size_t)N_NODES * 4;
    size_t msbytes = zb_ctr + zb_bkt + zb_cnt1 + zb_cnt2 + 2 * zb_need;
    char* zsmall = alloc(msbytes);
    int*   n1ctr   = (int*)zsmall;
    int*   n0ctr   = n1ctr + 1;
    int*   ectr1   = n1ctr + 2;
    int*   ectr2   = n1ctr + 3;
    int*   bkt2cnt = (int*)(zsmall + zb_ctr);
    float* cnt1    = (float*)(zsmall + zb_ctr + zb_bkt);
    float* cnt2    = (float*)(zsmall + zb_ctr + zb_bkt + zb_cnt1);
    int*   need1   = (int*)(zsmall + zb_ctr + zb_bkt + zb_cnt1 + zb_cnt2);
    int*   need0   = (int*)((char*)need1 + zb_need);

    // --- Amsg region (zeroed in N1) ---
    size_t zb_amsg1 = (size_t)CAP1 * MSGW * 4;
    size_t zb_amsg2 = (size_t)BATCH * MSGW * 4;
    char* amsg = alloc(zb_amsg1 + zb_amsg2);
    float* Amsg1 = (float*)amsg;
    float* Amsg2 = (float*)(amsg + zb_amsg1);
    int nzA2 = (int)((zb_amsg1 + zb_amsg2) / 32);   // 32 B per zero thread

    int* map1  = (int*)alloc(N_NODES * 4);
    int* map0  = (int*)alloc(N_NODES * 4);
    int* idx1  = (int*)alloc(CAP1 * 4);
    int* idx0  = (int*)alloc(CAP0 * 4);
    int* elist1 = (int*)alloc(ECAP1 * 4);
    int* elist2 = (int*)alloc(ECAP2 * 4);
    int* bkt2   = (int*)alloc((size_t)NTILE1 * BKT2CAP * 4);   // 256 KB
    float* h0c = (float*)alloc((size_t)CAP0 * HID * 4);
    float* h1c = (float*)alloc((size_t)CAP1 * HID * 4);
    unsigned short* w1s = (unsigned short*)alloc((size_t)IN_DIM * HID * 2);
    unsigned short* B1s = (unsigned short*)alloc((size_t)KCAT * HID * 2);
    unsigned short* B2s = (unsigned short*)alloc((size_t)KCAT * HID * 2);
    unsigned short* W2t = (unsigned short*)alloc((size_t)HID * OUT_DIM * 2);
    (void)ws_size; (void)in_sizes; (void)n_in; (void)out_size;

    const int NB = 256;

    // N0: zero flags/counters/cnts/buckets
    hipMemsetAsync(zsmall, 0, msbytes, stream);
    // N1: Amsg zero + weight prep + mark1c
    int n1_total = nzA2 + P1n + 2 * P2n + PW2n + N_EDGES;
    prep_mark1<<<dim3((n1_total + NB - 1) / NB), NB, 0, stream>>>(
        (uint4*)amsg, nzA2, W1, c1root, c1W, c2root, c2W, W2,
        w1s, B1s, B2s, W2t, ei, need1, elist2, ectr2);
    // N2: mark0c + compact S1
    int n2_total = N_EDGES + N_NODES;
    mark0_compact1<<<dim3((n2_total + NB - 1) / NB), NB, 0, stream>>>(
        ei, need1, need0, elist1, ectr1, idx1, map1, n1ctr);
    // N3: compact S0 + bucket conv2 edges by src tile
    int n3_total = N_NODES + ECAP2;
    compact0_bucket<<<dim3((n3_total + NB - 1) / NB), NB, 0, stream>>>(
        map1, need0, idx0, map0, n0ctr, ei, elist2, ectr2, bkt2cnt, bkt2);
    // N4: h0c = relu(x[S0] @ W1 + b1)
    gemm1_mfma<<<dim3(CAP0 / 64), NB, 0, stream>>>(x, idx0, w1s, b1, h0c, n0ctr, CAP0);
    // N5: scatter conv1 messages (grid-stride, 2048 blocks)
    scatter_gs<<<dim3(2048), NB, 0, stream>>>(ei, et, elist1, ectr1, ECAP1,
                                              map0, map1, h0c, Amsg1, cnt1, CAP1);
    // N6: conv1 + fused conv2-message scatter
    conv1_scat<<<dim3(CAP1 / 64), NB, 0, stream>>>(
        h0c, idx1, map0, map1, Amsg1, cnt1, CAP1, B1s, c1bias, h1c, n1ctr, CAP1,
        ei, et, bkt2cnt, bkt2, Amsg2, cnt2);
    // N7: conv2 + lin2 + relu + classifier
    conv2_fused<<<dim3(BATCH / 64), NB, 0, stream>>>(h1c, map1, Amsg2, cnt2,
                                                     B2s, c2bias, W2t, b2, Wc, bc, out);
}

// Round 14
// 379.336 us; speedup vs baseline: 1.0160x; 1.0146x over previous
//
#include <hip/hip_runtime.h>

// RGCN pruned to the 2-hop cone of the first 1024 nodes.
// R13: REVERT to R11 champion (379.4us, absmax 1.95e-3). R12's scatter2
// fusion regressed (+5.5us: conv1 LDS 33.8KB halved occupancy, extra bucket
// pass, serialized epilogue scatter). 9 graph nodes:
//   N0 memset(flags/ctrs) | N1 prep+Amsg0+mark1 | N2 mark0+compactS1 |
//   N3 compactS0 | N4 gemm1-MFMA | N5 scatter1 | N6 conv1-MFMA |
//   N7 scatter2 | N8 conv2+lin2+cls fused.
// Session cost model: ~180us harness poison-fill + ~90us dispatch chain +
// ~110us kernel work. No kernel near an HBM/MFMA ceiling; floor-dominated.

#define N_NODES 100000
#define N_EDGES 400000
#define IN_DIM  768
#define HID     256
#define OUT_DIM 128
#define NREL    3
#define BATCH   1024
#define KCAT    1024   // HID*(NREL+1)
#define MSGW    768    // NREL*HID
#define CAP0    32768  // |S0| ~23K
#define CAP1    8192   // |S1| ~5K
#define ECAP1   32768  // edges into S1 ~20K
#define ECAP2   8192   // edges into S2 ~4.1K

typedef __attribute__((ext_vector_type(8))) short bf16x8;
typedef __attribute__((ext_vector_type(4))) float f32x4;

static __device__ __forceinline__ int imin(int a, int b) { return a < b ? a : b; }

static __device__ __forceinline__ unsigned short f2bf(float f) {
    union { float f; unsigned int u; } v; v.f = f;
    unsigned int r = v.u + 0x7FFFu + ((v.u >> 16) & 1u);   // RNE
    return (unsigned short)(r >> 16);
}

#define P1n  ((IN_DIM * HID) / 8)    // 24576 w1s threads
#define P2n  ((KCAT * HID) / 8)      // 32768 per B1s/B2s
#define PW2n ((HID * OUT_DIM) / 8)   // 4096 W2t threads

// ---------------- N1: Amsg zero + all weight prep + mark1c ----------------
__global__ __launch_bounds__(256) void prep_mark1(
    uint4* __restrict__ zp, int nzA,
    const float* __restrict__ W1,
    const float* __restrict__ c1root, const float* __restrict__ c1W,
    const float* __restrict__ c2root, const float* __restrict__ c2W,
    const float* __restrict__ W2,
    unsigned short* __restrict__ w1s,
    unsigned short* __restrict__ B1s,
    unsigned short* __restrict__ B2s,
    unsigned short* __restrict__ W2t,
    const int* __restrict__ ei, int* __restrict__ need1,
    int* __restrict__ elist2, int* __restrict__ ectr2)
{
    int t = blockIdx.x * blockDim.x + threadIdx.x;
    if (t < nzA) { zp[t] = make_uint4(0u, 0u, 0u, 0u); return; }
    int u = t - nzA;
    if (u < P1n) {
        int base = u * 8;
        int j0 = base & 31, c = (base >> 5) & 255, s = base >> 13;
        unsigned int pk[4];
        #pragma unroll
        for (int q = 0; q < 4; q++) {
            unsigned short lo = f2bf(W1[((s * 32 + j0 + 2 * q) << 8) + c]);
            unsigned short hi = f2bf(W1[((s * 32 + j0 + 2 * q + 1) << 8) + c]);
            pk[q] = (unsigned int)lo | ((unsigned int)hi << 16);
        }
        *(uint4*)&w1s[base] = make_uint4(pk[0], pk[1], pk[2], pk[3]);
        return;
    }
    u -= P1n;
    if (u < 2 * P2n) {
        int which2 = u >= P2n;
        const float* root = which2 ? c2root : c1root;
        const float* Wr   = which2 ? c2W : c1W;
        unsigned short* dst = which2 ? B2s : B1s;
        int base = (u - (which2 ? P2n : 0)) * 8;
        int j0 = base & 31, c = (base >> 5) & 255, s = base >> 13;
        int k0 = s * 32 + j0;
        unsigned int pk[4];
        #pragma unroll
        for (int q = 0; q < 4; q++) {
            int ka = k0 + 2 * q, kb = ka + 1;
            float va = (ka < HID) ? root[(ka << 8) + c] : Wr[((ka - HID) << 8) + c];
            float vb = (kb < HID) ? root[(kb << 8) + c] : Wr[((kb - HID) << 8) + c];
            pk[q] = (unsigned int)f2bf(va) | ((unsigned int)f2bf(vb) << 16);
        }
        *(uint4*)&dst[base] = make_uint4(pk[0], pk[1], pk[2], pk[3]);
        return;
    }
    u -= 2 * P2n;
    if (u < PW2n) {
        // W2t[((s*8 + f)*64 + l)*8 + j] = bf16(W2[s*32 + (l>>4)*8 + j][f*16 + (l&15)])
        int s = u >> 9, f = (u >> 6) & 7, l = u & 63;
        int kb = s * 32 + ((l >> 4) << 3);
        int c  = (f << 4) + (l & 15);
        unsigned int pk[4];
        #pragma unroll
        for (int q = 0; q < 4; q++) {
            unsigned short lo = f2bf(W2[(size_t)(kb + 2 * q)     * OUT_DIM + c]);
            unsigned short hi = f2bf(W2[(size_t)(kb + 2 * q + 1) * OUT_DIM + c]);
            pk[q] = (unsigned int)lo | ((unsigned int)hi << 16);
        }
        *(uint4*)&W2t[(size_t)u * 8] = make_uint4(pk[0], pk[1], pk[2], pk[3]);
        return;
    }
    u -= PW2n;
    if (u < N_EDGES) {
        if (ei[N_EDGES + u] < BATCH) {
            need1[ei[u]] = 1;   // benign same-value race
            int p = atomicAdd(ectr2, 1);
            if (p < ECAP2) elist2[p] = u;
        }
    }
}

// ---------------- N2: mark0c + compact S1 (both depend only on need1) ----------------
__global__ void mark0_compact1(const int* __restrict__ ei, const int* __restrict__ need1,
                               int* __restrict__ need0,
                               int* __restrict__ elist1, int* __restrict__ ectr1,
                               int* __restrict__ idx1, int* __restrict__ map1,
                               int* __restrict__ n1ctr) {
    int t = blockIdx.x * blockDim.x + threadIdx.x;
    if (t < N_EDGES) {
        int d = ei[N_EDGES + t];
        if (d < BATCH || need1[d]) {
            need0[ei[t]] = 1;
            int p = atomicAdd(ectr1, 1);
            if (p < ECAP1) elist1[p] = t;
        }
        return;
    }
    int i = t - N_EDGES;
    if (i < N_NODES) {
        if ((i < BATCH) | need1[i]) {
            int p = atomicAdd(n1ctr, 1);
            if (p < CAP1) { idx1[p] = i; map1[i] = p; } else map1[i] = -1;
        } else map1[i] = -1;
    }
}

// ---------------- N3: compact S0 (needs need0 complete + map1) ----------------
__global__ void compact0(const int* __restrict__ map1, const int* __restrict__ need0,
                         int* __restrict__ idx0, int* __restrict__ map0,
                         int* __restrict__ n0ctr) {
    int i = blockIdx.x * blockDim.x + threadIdx.x;
    if (i >= N_NODES) return;
    if ((map1[i] >= 0) | need0[i]) {
        int p = atomicAdd(n0ctr, 1);
        if (p < CAP0) { idx0[p] = i; map0[i] = p; } else map0[i] = -1;
    } else map0[i] = -1;
}

// ---------------- scatter over compacted edge list ----------------
__global__ void scatter_c(const int* __restrict__ ei, const int* __restrict__ et,
                          const int* __restrict__ elist, const int* __restrict__ ectr, int ecap,
                          const int* __restrict__ mapSrc, const int* __restrict__ mapDst,
                          const float* __restrict__ hsrc,
                          float* __restrict__ Amsg, float* __restrict__ cnt,
                          int cntStride) {
    int g = blockIdx.x * blockDim.x + threadIdx.x;
    int ii = g >> 6, lane = g & 63;
    int n = imin(*ectr, ecap);
    if (ii >= n) return;
    int e = elist[ii];
    int d = ei[N_EDGES + e];
    int row = mapDst ? mapDst[d] : d;
    if (row < 0) return;
    int s = mapSrc[ei[e]];
    if (s < 0) return;
    int r = et[e];
    float4 v = *(const float4*)(hsrc + (size_t)s * HID + lane * 4);
    float* dp = Amsg + (size_t)row * MSGW + (size_t)r * HID + lane * 4;
    atomicAdd(dp + 0, v.x);
    atomicAdd(dp + 1, v.y);
    atomicAdd(dp + 2, v.z);
    atomicAdd(dp + 3, v.w);
    if (lane == 0) atomicAdd(cnt + (size_t)r * cntStride + row, 1.0f);
}

// ---------------- N4: linear1 (champion) ----------------
__global__ __launch_bounds__(256) void gemm1_mfma(
    const float* __restrict__ x, const int* __restrict__ idx0,
    const unsigned short* __restrict__ w1s, const float* __restrict__ b1,
    float* __restrict__ h0c, const int* __restrict__ Mptr, int Mcap)
{
    int M = imin(*Mptr, Mcap);
    int bm = blockIdx.x * 64;
    if (bm >= M) return;

    __shared__ unsigned short As[64][40];
    __shared__ unsigned short Bs[256][40];

    int tid = threadIdx.x;
    int w = tid >> 6, lane = tid & 63;
    int l16 = lane & 15, lhi = lane >> 4;

    int ar = tid >> 2, ac = tid & 3;
    int gr = idx0[imin(bm + ar, M - 1)];
    const float* aptr = x + (size_t)gr * IN_DIM + ac * 8;

    f32x4 acc[16];
    #pragma unroll
    for (int i = 0; i < 16; i++) acc[i] = (f32x4)0.0f;

    for (int k0 = 0; k0 < IN_DIM; k0 += 32) {
        float4 a0 = *(const float4*)(aptr + k0);
        float4 a1 = *(const float4*)(aptr + k0 + 4);
        unsigned int p0 = (unsigned int)f2bf(a0.x) | ((unsigned int)f2bf(a0.y) << 16);
        unsigned int p1 = (unsigned int)f2bf(a0.z) | ((unsigned int)f2bf(a0.w) << 16);
        unsigned int p2 = (unsigned int)f2bf(a1.x) | ((unsigned int)f2bf(a1.y) << 16);
        unsigned int p3 = (unsigned int)f2bf(a1.z) | ((unsigned int)f2bf(a1.w) << 16);
        *(uint4*)&As[ar][ac * 8] = make_uint4(p0, p1, p2, p3);

        const uint4* bsrc = (const uint4*)(w1s + ((size_t)(k0 >> 5) * 256 + tid) * 32);
        int bswz = (tid >> 3) & 3;
        uint4 b0 = bsrc[0], b1v = bsrc[1], b2 = bsrc[2], b3 = bsrc[3];
        *(uint4*)&Bs[tid][(0 ^ bswz) * 8] = b0;
        *(uint4*)&Bs[tid][(1 ^ bswz) * 8] = b1v;
        *(uint4*)&Bs[tid][(2 ^ bswz) * 8] = b2;
        *(uint4*)&Bs[tid][(3 ^ bswz) * 8] = b3;
        __syncthreads();

        bf16x8 af = *(bf16x8*)&As[w * 16 + l16][lhi * 8];
        #pragma unroll
        for (int f = 0; f < 16; f++) {
            int col = f * 16 + l16;
            bf16x8 bf = *(bf16x8*)&Bs[col][(lhi ^ ((col >> 3) & 3)) * 8];
            acc[f] = __builtin_amdgcn_mfma_f32_16x16x32_bf16(af, bf, acc[f], 0, 0, 0);
        }
        __syncthreads();
    }

    #pragma unroll
    for (int f = 0; f < 16; f++) {
        int col = f * 16 + l16;
        float bb = b1[col];
        #pragma unroll
        for (int reg = 0; reg < 4; reg++) {
            int row = bm + w * 16 + lhi * 4 + reg;
            if (row < M) h0c[(size_t)row * HID + col] = fmaxf(acc[f][reg] + bb, 0.0f);
        }
    }
}

// ---------------- N6: conv1 GEMM (champion) ----------------
__global__ __launch_bounds__(256) void conv_mfma(
    const float* __restrict__ hsrc,
    const int* __restrict__ idx, const int* __restrict__ map,
    const float* __restrict__ Amsg,
    const float* __restrict__ cnt, int cntStride,
    const unsigned short* __restrict__ Bt, const float* __restrict__ bias,
    float* __restrict__ Cout, const int* __restrict__ Mptr, int Mcap)
{
    int M = Mptr ? imin(*Mptr, Mcap) : Mcap;
    int bm = blockIdx.x * 64;
    if (bm >= M) return;

    __shared__ unsigned short As[64][40];
    __shared__ unsigned short Bs[256][40];

    int tid = threadIdx.x;
    int w = tid >> 6, lane = tid & 63;
    int l16 = lane & 15, lhi = lane >> 4;

    int ar = tid >> 2, ac = tid & 3;
    int row = imin(bm + ar, M - 1);
    int node = idx ? idx[row] : row;
    int grow = map[node]; if (grow < 0) grow = 0;
    const float* rootp = hsrc + (size_t)grow * HID + ac * 8;
    const float* msgp  = Amsg + (size_t)row * MSGW + ac * 8;
    float sc[NREL];
    #pragma unroll
    for (int r = 0; r < NREL; r++)
        sc[r] = 1.0f / fmaxf(cnt[(size_t)r * cntStride + row], 1.0f);

    f32x4 acc[16];
    #pragma unroll
    for (int i = 0; i < 16; i++) acc[i] = (f32x4)0.0f;

    for (int k0 = 0; k0 < KCAT; k0 += 32) {
        float4 a0, a1;
        if (k0 < HID) {
            a0 = *(const float4*)(rootp + k0);
            a1 = *(const float4*)(rootp + k0 + 4);
        } else {
            float s = sc[(k0 - HID) >> 8];
            a0 = *(const float4*)(msgp + (k0 - HID));
            a1 = *(const float4*)(msgp + (k0 - HID) + 4);
            a0.x *= s; a0.y *= s; a0.z *= s; a0.w *= s;
            a1.x *= s; a1.y *= s; a1.z *= s; a1.w *= s;
        }
        unsigned int p0 = (unsigned int)f2bf(a0.x) | ((unsigned int)f2bf(a0.y) << 16);
        unsigned int p1 = (unsigned int)f2bf(a0.z) | ((unsigned int)f2bf(a0.w) << 16);
        unsigned int p2 = (unsigned int)f2bf(a1.x) | ((unsigned int)f2bf(a1.y) << 16);
        unsigned int p3 = (unsigned int)f2bf(a1.z) | ((unsigned int)f2bf(a1.w) << 16);
        *(uint4*)&As[ar][ac * 8] = make_uint4(p0, p1, p2, p3);

        const uint4* bsrc = (const uint4*)(Bt + ((size_t)(k0 >> 5) * 256 + tid) * 32);
        int bswz = (tid >> 3) & 3;
        uint4 b0 = bsrc[0], b1v = bsrc[1], b2 = bsrc[2], b3 = bsrc[3];
        *(uint4*)&Bs[tid][(0 ^ bswz) * 8] = b0;
        *(uint4*)&Bs[tid][(1 ^ bswz) * 8] = b1v;
        *(uint4*)&Bs[tid][(2 ^ bswz) * 8] = b2;
        *(uint4*)&Bs[tid][(3 ^ bswz) * 8] = b3;
        __syncthreads();

        bf16x8 af = *(bf16x8*)&As[w * 16 + l16][lhi * 8];
        #pragma unroll
        for (int f = 0; f < 16; f++) {
            int col = f * 16 + l16;
            bf16x8 bf = *(bf16x8*)&Bs[col][(lhi ^ ((col >> 3) & 3)) * 8];
            acc[f] = __builtin_amdgcn_mfma_f32_16x16x32_bf16(af, bf, acc[f], 0, 0, 0);
        }
        __syncthreads();
    }

    #pragma unroll
    for (int f = 0; f < 16; f++) {
        int col = f * 16 + l16;
        float bb = bias[col];
        #pragma unroll
        for (int reg = 0; reg < 4; reg++) {
            int r = bm + w * 16 + lhi * 4 + reg;
            if (r < M) Cout[(size_t)r * HID + col] = acc[f][reg] + bb;
        }
    }
}

// ---------------- N8: conv2 + lin2 + relu + classifier, fused ----------------
__global__ __launch_bounds__(256) void conv2_fused(
    const float* __restrict__ hsrc, const int* __restrict__ map,
    const float* __restrict__ Amsg, const float* __restrict__ cnt,
    const unsigned short* __restrict__ Bt, const float* __restrict__ c2bias,
    const unsigned short* __restrict__ W2t, const float* __restrict__ b2,
    const float* __restrict__ Wc, const float* __restrict__ bc,
    float* __restrict__ out)
{
    int bm = blockIdx.x * 64;

    __shared__ unsigned short As[64][40];
    __shared__ unsigned short Bs[256][40];
    __shared__ unsigned short h2s[64][264];   // 256 cols + 8 pad (2-way banks)

    int tid = threadIdx.x;
    int w = tid >> 6, lane = tid & 63;
    int l16 = lane & 15, lhi = lane >> 4;

    int ar = tid >> 2, ac = tid & 3;
    int row = bm + ar;                         // always < BATCH
    int grow = map[row]; if (grow < 0) grow = 0;
    const float* rootp = hsrc + (size_t)grow * HID + ac * 8;
    const float* msgp  = Amsg + (size_t)row * MSGW + ac * 8;
    float sc[NREL];
    #pragma unroll
    for (int r = 0; r < NREL; r++)
        sc[r] = 1.0f / fmaxf(cnt[(size_t)r * BATCH + row], 1.0f);

    f32x4 acc[16];
    #pragma unroll
    for (int i = 0; i < 16; i++) acc[i] = (f32x4)0.0f;

    for (int k0 = 0; k0 < KCAT; k0 += 32) {
        float4 a0, a1;
        if (k0 < HID) {
            a0 = *(const float4*)(rootp + k0);
            a1 = *(const float4*)(rootp + k0 + 4);
        } else {
            float s = sc[(k0 - HID) >> 8];
            a0 = *(const float4*)(msgp + (k0 - HID));
            a1 = *(const float4*)(msgp + (k0 - HID) + 4);
            a0.x *= s; a0.y *= s; a0.z *= s; a0.w *= s;
            a1.x *= s; a1.y *= s; a1.z *= s; a1.w *= s;
        }
        unsigned int p0 = (unsigned int)f2bf(a0.x) | ((unsigned int)f2bf(a0.y) << 16);
        unsigned int p1 = (unsigned int)f2bf(a0.z) | ((unsigned int)f2bf(a0.w) << 16);
        unsigned int p2 = (unsigned int)f2bf(a1.x) | ((unsigned int)f2bf(a1.y) << 16);
        unsigned int p3 = (unsigned int)f2bf(a1.z) | ((unsigned int)f2bf(a1.w) << 16);
        *(uint4*)&As[ar][ac * 8] = make_uint4(p0, p1, p2, p3);

        const uint4* bsrc = (const uint4*)(Bt + ((size_t)(k0 >> 5) * 256 + tid) * 32);
        int bswz = (tid >> 3) & 3;
        uint4 b0 = bsrc[0], b1v = bsrc[1], b2v = bsrc[2], b3 = bsrc[3];
        *(uint4*)&Bs[tid][(0 ^ bswz) * 8] = b0;
        *(uint4*)&Bs[tid][(1 ^ bswz) * 8] = b1v;
        *(uint4*)&Bs[tid][(2 ^ bswz) * 8] = b2v;
        *(uint4*)&Bs[tid][(3 ^ bswz) * 8] = b3;
        __syncthreads();

        bf16x8 af = *(bf16x8*)&As[w * 16 + l16][lhi * 8];
        #pragma unroll
        for (int f = 0; f < 16; f++) {
            int col = f * 16 + l16;
            bf16x8 bf = *(bf16x8*)&Bs[col][(lhi ^ ((col >> 3) & 3)) * 8];
            acc[f] = __builtin_amdgcn_mfma_f32_16x16x32_bf16(af, bf, acc[f], 0, 0, 0);
        }
        __syncthreads();
    }

    // stage h2 tile (bias added, bf16) into LDS
    #pragma unroll
    for (int f = 0; f < 16; f++) {
        int col = f * 16 + l16;
        float bb = c2bias[col];
        #pragma unroll
        for (int reg = 0; reg < 4; reg++)
            h2s[w * 16 + lhi * 4 + reg][col] = f2bf(acc[f][reg] + bb);
    }
    __syncthreads();

    // lin2: h3 = relu(h2 @ W2 + b2)  -- 8 K-steps x 8 col-frags, MFMA
    f32x4 acc2[8];
    #pragma unroll
    for (int i = 0; i < 8; i++) acc2[i] = (f32x4)0.0f;
    for (int s = 0; s < 8; s++) {
        bf16x8 af = *(bf16x8*)&h2s[w * 16 + l16][s * 32 + lhi * 8];
        #pragma unroll
        for (int f = 0; f < 8; f++) {
            bf16x8 bf = *(const bf16x8*)(W2t + ((size_t)(s * 8 + f) * 64 + lane) * 8);
            acc2[f] = __builtin_amdgcn_mfma_f32_16x16x32_bf16(af, bf, acc2[f], 0, 0, 0);
        }
    }

    // classifier: logits[row] = sum_col relu(h3) * Wc + bc
    float p0[4] = {0.f, 0.f, 0.f, 0.f}, p1[4] = {0.f, 0.f, 0.f, 0.f};
    #pragma unroll
    for (int f = 0; f < 8; f++) {
        int col = f * 16 + l16;
        float w0 = Wc[col * 2 + 0], w1 = Wc[col * 2 + 1];
        float bb = b2[col];
        #pragma unroll
        for (int reg = 0; reg < 4; reg++) {
            float h = fmaxf(acc2[f][reg] + bb, 0.0f);
            p0[reg] += h * w0;
            p1[reg] += h * w1;
        }
    }
    #pragma unroll
    for (int o = 1; o <= 8; o <<= 1) {
        #pragma unroll
        for (int reg = 0; reg < 4; reg++) {
            p0[reg] += __shfl_xor(p0[reg], o);
            p1[reg] += __shfl_xor(p1[reg], o);
        }
    }
    if (l16 == 0) {
        #pragma unroll
        for (int reg = 0; reg < 4; reg++) {
            int r = bm + w * 16 + lhi * 4 + reg;
            out[r * 2 + 0] = p0[reg] + bc[0];
            out[r * 2 + 1] = p1[reg] + bc[1];
        }
    }
}

// ---------------- host ----------------

extern "C" void kernel_launch(void* const* d_in, const int* in_sizes, int n_in,
                              void* d_out, int out_size, void* d_ws, size_t ws_size,
                              hipStream_t stream) {
    const float* x      = (const float*)d_in[0];
    const int*   ei     = (const int*)d_in[1];
    const int*   et     = (const int*)d_in[2];
    const float* W1     = (const float*)d_in[4];
    const float* b1     = (const float*)d_in[5];
    const float* c1W    = (const float*)d_in[6];
    const float* c1root = (const float*)d_in[7];
    const float* c1bias = (const float*)d_in[8];
    const float* c2W    = (const float*)d_in[9];
    const float* c2root = (const float*)d_in[10];
    const float* c2bias = (const float*)d_in[11];
    const float* W2     = (const float*)d_in[12];
    const float* b2     = (const float*)d_in[13];
    const float* Wc     = (const float*)d_in[14];
    const float* bc     = (const float*)d_in[15];
    float* out = (float*)d_out;

    char* ws = (char*)d_ws;
    size_t off = 0;
    auto alloc = [&](size_t bytes) -> char* {
        char* p = ws + off;
        off = (off + bytes + 255) & ~(size_t)255;
        return p;
    };

    // --- memset region (node 0): ctrs | cnt1 | cnt2 | need1 | need0 ---
    size_t zb_ctr  = 16;
    size_t zb_cnt1 = (size_t)NREL * CAP1 * 4;
    size_t zb_cnt2 = (size_t)NREL * BATCH * 4;
    size_t zb_need = (size_t)N_NODES * 4;
    size_t msbytes = zb_ctr + zb_cnt1 + zb_cnt2 + 2 * zb_need;   // ~0.92 MB
    char* zsmall = alloc(msbytes);
    int*   n1ctr = (int*)zsmall;
    int*   n0ctr = n1ctr + 1;
    int*   ectr1 = n1ctr + 2;
    int*   ectr2 = n1ctr + 3;
    float* cnt1  = (float*)(zsmall + zb_ctr);
    float* cnt2  = (float*)(zsmall + zb_ctr + zb_cnt1);
    int*   need1 = (int*)(zsmall + zb_ctr + zb_cnt1 + zb_cnt2);
    int*   need0 = (int*)((char*)need1 + zb_need);

    // --- Amsg region (zeroed in N1) ---
    size_t zb_amsg1 = (size_t)CAP1 * MSGW * 4;
    size_t zb_amsg2 = (size_t)BATCH * MSGW * 4;
    char* amsg = alloc(zb_amsg1 + zb_amsg2);
    float* Amsg1 = (float*)amsg;
    float* Amsg2 = (float*)(amsg + zb_amsg1);
    int nzA = (int)((zb_amsg1 + zb_amsg2) / 16);

    int* map1  = (int*)alloc(N_NODES * 4);
    int* map0  = (int*)alloc(N_NODES * 4);
    int* idx1  = (int*)alloc(CAP1 * 4);
    int* idx0  = (int*)alloc(CAP0 * 4);
    int* elist1 = (int*)alloc(ECAP1 * 4);
    int* elist2 = (int*)alloc(ECAP2 * 4);
    float* h0c = (float*)alloc((size_t)CAP0 * HID * 4);
    float* h1c = (float*)alloc((size_t)CAP1 * HID * 4);
    unsigned short* w1s = (unsigned short*)alloc((size_t)IN_DIM * HID * 2);
    unsigned short* B1s = (unsigned short*)alloc((size_t)KCAT * HID * 2);
    unsigned short* B2s = (unsigned short*)alloc((size_t)KCAT * HID * 2);
    unsigned short* W2t = (unsigned short*)alloc((size_t)HID * OUT_DIM * 2);
    (void)ws_size; (void)in_sizes; (void)n_in; (void)out_size;

    const int NB = 256;

    // N0: zero flags/counters/cnts (small)
    hipMemsetAsync(zsmall, 0, msbytes, stream);
    // N1: Amsg zero + weight prep (w1s,B1s,B2s,W2t) + mark1c
    int n1_total = nzA + P1n + 2 * P2n + PW2n + N_EDGES;
    prep_mark1<<<dim3((n1_total + NB - 1) / NB), NB, 0, stream>>>(
        (uint4*)amsg, nzA, W1, c1root, c1W, c2root, c2W, W2,
        w1s, B1s, B2s, W2t, ei, need1, elist2, ectr2);
    // N2: mark0c + compact S1
    int n2_total = N_EDGES + N_NODES;
    mark0_compact1<<<dim3((n2_total + NB - 1) / NB), NB, 0, stream>>>(
        ei, need1, need0, elist1, ectr1, idx1, map1, n1ctr);
    // N3: compact S0
    compact0<<<dim3((N_NODES + NB - 1) / NB), NB, 0, stream>>>(map1, need0, idx0, map0, n0ctr);
    // N4: h0c = relu(x[S0] @ W1 + b1)
    gemm1_mfma<<<dim3(CAP0 / 64), NB, 0, stream>>>(x, idx0, w1s, b1, h0c, n0ctr, CAP0);
    // N5-N6: conv1
    scatter_c<<<dim3(ECAP1 * 64 / NB), NB, 0, stream>>>(ei, et, elist1, ectr1, ECAP1,
                                                        map0, map1, h0c, Amsg1, cnt1, CAP1);
    conv_mfma<<<dim3(CAP1 / 64), NB, 0, stream>>>(h0c, idx1, map0, Amsg1, cnt1, CAP1,
                                                  B1s, c1bias, h1c, n1ctr, CAP1);
    // N7: scatter for conv2
    scatter_c<<<dim3(ECAP2 * 64 / NB), NB, 0, stream>>>(ei, et, elist2, ectr2, ECAP2,
                                                        map1, nullptr, h1c, Amsg2, cnt2, BATCH);
    // N8: conv2 + lin2 + relu + classifier
    conv2_fused<<<dim3(BATCH / 64), NB, 0, stream>>>(h1c, map1, Amsg2, cnt2,
                                                     B2s, c2bias, W2t, b2, Wc, bc, out);
}